// Round 21
// baseline (355.135 us; speedup 1.0000x reference)
//
#include <hip/hip_runtime.h>
#include <hip/hip_bf16.h>

// Performer (FAVOR+) forward. Round 21: R17 base (301.5us best) + GEMM
// 2-phase split per K-tile (T3-lite): same 4-deep buffers/swizzle/staging,
// per K-tile {waitbar(4), stageA, Bfrags+A(ti0-3), 16 MFMA} then {bar,
// stageB, A(ti4-7), 16 MFMA}, setprio around MFMA clusters (T5).
// Numerics bit-identical to R17. Middle kernels R17-identical.
// B=4, S=4096, D=1024, H=16, K=64, M=128.

#define B_  4
#define S_  4096
#define H_  16

#define SCALE_X 0.3535533905932738f     // 64^-0.25
#define CM      0.08838834764831845f    // 128^-0.5

typedef __attribute__((ext_vector_type(8))) short bf16x8;
typedef __attribute__((ext_vector_type(4))) short s16x4;
typedef __attribute__((ext_vector_type(8))) unsigned short u16x8;
typedef __attribute__((ext_vector_type(8))) _Float16 f16x8;
typedef __attribute__((ext_vector_type(4))) _Float16 f16x4;
typedef __attribute__((ext_vector_type(4))) float f32x4;

// ---- ws layout (float units) ----
#define OFF_A    ((size_t)0)          // kproj16 then qproj16 (fp16, 32MB)
#define OFF_B    ((size_t)16777216)   // vproj16 (fp16)
#define OFF_X    ((size_t)33554432)   // union: WT fp16 / k1part(131072)
#define OFF_KV   ((size_t)37814272)   // kvT bf16: 524288 ush
#define OFF_K1   ((size_t)38338560)   // 64*128 f32
#define OFF_BM   ((size_t)38346752)   // 512 block maxes
#define OFF_ST   ((size_t)38347264)   // stab scalar
#define OFF_A16  ((size_t)38347776)   // 8388608 f32: GEMM A staging / kvpartT
// total 46736384 f32 = 186.9 MB

__device__ __forceinline__ unsigned short f2bf(float x) {
  union { __hip_bfloat16 b; unsigned short u; } c;
  c.b = __float2bfloat16(x);
  return c.u;
}

#define MFMAB(ACC, A, B)                                               \
  ACC = __builtin_amdgcn_mfma_f32_16x16x32_bf16(A, B, ACC, 0, 0, 0)

#define GLDS(GP, LP)                                                  \
  __builtin_amdgcn_global_load_lds(                                   \
      (const __attribute__((address_space(1))) unsigned int*)(GP),    \
      (__attribute__((address_space(3))) unsigned int*)(LP), 16, 0, 0)

// load P-operand fragment (B for wx): lane supplies P[m][kb..kb+7] as bf16
__device__ __forceinline__ void load_pfrag(const float* __restrict__ proj, int m,
                                           int kb, bf16x8* ph) {
  const float* p = proj + m * 64 + kb;
  float4 a = *reinterpret_cast<const float4*>(p);
  float4 b = *reinterpret_cast<const float4*>(p + 4);
  float v[8] = {a.x, a.y, a.z, a.w, b.x, b.y, b.z, b.w};
  bf16x8 h;
#pragma unroll
  for (int j = 0; j < 8; ++j) h[j] = (short)f2bf(v[j]);
  *ph = h;
}

// Stage one X row-chunk FROM REGISTERS: scale, bf16, chunk-XOR LDS write.
#define STAGE_XR(XV, WANT_DIAG)                                           \
  {                                                                       \
    f16x8 xv_ = (XV);                                                     \
    u16x8 hh_;                                                            \
    float sq_ = 0.f;                                                      \
    _Pragma("unroll") for (int j = 0; j < 8; ++j) {                       \
      float vf_ = (float)xv_[j] * SCALE_X;                                \
      sq_ += vf_ * vf_;                                                   \
      hh_[j] = f2bf(vf_);                                                 \
    }                                                                     \
    *reinterpret_cast<u16x8*>(&Xh[srow][xc]) = hh_;                       \
    if (WANT_DIAG) {                                                      \
      sq_ += __shfl_xor(sq_, 1);                                          \
      sq_ += __shfl_xor(sq_, 2);                                          \
      sq_ += __shfl_xor(sq_, 4);                                          \
      if ((tid & 7) == 0) diags[srow] = 0.5f * sq_;                       \
    }                                                                     \
  }

// wx MFMA block: 2 st x 2 ks x 2 mtl, single bf16 MFMA each.
#define WX_COMPUTE(WX)                                                       \
  _Pragma("unroll") for (int st_ = 0; st_ < 2; ++st_)                        \
  _Pragma("unroll") for (int ks_ = 0; ks_ < 2; ++ks_) {                      \
    const int rr_ = st_ * 16 + l15;                                          \
    const int cc_ = ((ks_ * 4 + lg) ^ (l15 & 7)) << 3;                       \
    bf16x8 xh_ = *reinterpret_cast<const bf16x8*>(&Xh[rr_][cc_]);            \
    _Pragma("unroll") for (int mtl_ = 0; mtl_ < 2; ++mtl_)                   \
        MFMAB(WX[st_][mtl_], xh_, ph[mtl_][ks_]);                            \
  }

// ---------------------------------------------------------------------------
// f32 -> fp16 conversion pass (16777216 elements).
// ---------------------------------------------------------------------------
__global__ __launch_bounds__(256) void cvt_f16_kernel(
    const float* __restrict__ in, _Float16* __restrict__ out) {
  const size_t stride = (size_t)gridDim.x * 256 * 8;
  for (size_t i = ((size_t)blockIdx.x * 256 + threadIdx.x) * 8; i < 16777216UL;
       i += stride) {
    float4 a = *reinterpret_cast<const float4*>(in + i);
    float4 b = *reinterpret_cast<const float4*>(in + i + 4);
    f16x8 h;
    h[0] = (_Float16)a.x; h[1] = (_Float16)a.y;
    h[2] = (_Float16)a.z; h[3] = (_Float16)a.w;
    h[4] = (_Float16)b.x; h[5] = (_Float16)b.y;
    h[6] = (_Float16)b.z; h[7] = (_Float16)b.w;
    *reinterpret_cast<f16x8*>(out + i) = h;
  }
}

// ---------------------------------------------------------------------------
// Weight transform: W[1024 k][1024 n] f32 -> WT [n][k] fp16.
// ---------------------------------------------------------------------------
__global__ __launch_bounds__(256) void wt_f16_kernel(
    const float* __restrict__ W, _Float16* __restrict__ T) {
  __shared__ float t[32][33];
  const int tx = threadIdx.x & 31, ty = threadIdx.x >> 5;
  const int k0 = blockIdx.x * 32, n0 = blockIdx.y * 32;
#pragma unroll
  for (int i = 0; i < 4; ++i)
    t[ty + 8 * i][tx] = W[(size_t)(k0 + ty + 8 * i) * 1024 + n0 + tx];
  __syncthreads();
#pragma unroll
  for (int i = 0; i < 4; ++i)
    T[(size_t)(n0 + ty + 8 * i) * 1024 + k0 + tx] = (_Float16)t[tx][ty + 8 * i];
}

// ---------------------------------------------------------------------------
// Pipelined fp16 GEMM, 256x256 tile, 512 threads (8 waves = 2m x 4n of
// 128x64). BK=32, 4-deep LDS, issue-ahead 2, counted vmcnt(4) (wait placed
// BEFORE the phase's own stage: outstanding = A(kt+1)+B(kt+1) = 4 loads).
// 2 phases per K-tile: A-phase {stage A(kt+2), Bfrags + A ti0-3, 16 MFMA},
// B-phase {stage B(kt+2), A ti4-7, 16 MFMA}. setprio(1) around MFMA (T5).
// Race: writer (kt+2)&3 vs readers kt&3 (skew <1 phase) — distinct mod 4.
// Swizzle c ^ ((r>>1)&3) both sides (2-way banks, R11-verified).
// ---------------------------------------------------------------------------
template <int F16OUT>
__global__ __launch_bounds__(512) void gemm_lds(
    const _Float16* __restrict__ A16, const _Float16* __restrict__ BT,
    const float* __restrict__ bias, void* __restrict__ Cout) {
  __shared__ _Float16 As[4][256][32];
  __shared__ _Float16 Bs[4][256][32];
  const int tid = threadIdx.x;
  const int bid = blockIdx.x;
  const int m0 = (bid & 63) << 8;
  const int n0 = (bid >> 6) << 8;
  const int wave = tid >> 6, lane = tid & 63;
  const int wm = (wave >> 2) << 7;
  const int wn = (wave & 3) << 6;
  const int l15 = lane & 15, lg = lane >> 4;

  const int rlo = tid >> 2;
  const int cg = ((tid & 3) ^ ((rlo >> 1) & 3)) << 3;
  const int wqbase = wave << 10;

  const _Float16* pa = A16 + (size_t)(m0 + rlo) * 1024 + cg;
  const _Float16* pb = BT + (size_t)(n0 + rlo) * 1024 + cg;

  f32x4 acc[8][4];
#pragma unroll
  for (int i = 0; i < 8; ++i)
#pragma unroll
    for (int j = 0; j < 4; ++j) acc[i][j] = f32x4{0.f, 0.f, 0.f, 0.f};

#define STAGE_A(nb, kt)                                                   \
  {                                                                       \
    char* la = (char*)&As[nb][0][0] + wqbase;                             \
    GLDS(pa + (kt) * 32, la);                                             \
    GLDS(pa + (kt) * 32 + 131072, la + 8192);                             \
  }
#define STAGE_B(nb, kt)                                                   \
  {                                                                       \
    char* lb = (char*)&Bs[nb][0][0] + wqbase;                             \
    GLDS(pb + (kt) * 32, lb);                                             \
    GLDS(pb + (kt) * 32 + 131072, lb + 8192);                             \
  }

#define WAITBAR(N)                                                        \
  asm volatile("s_waitcnt vmcnt(" #N ")" ::: "memory");                   \
  __builtin_amdgcn_s_barrier();                                           \
  asm volatile("" ::: "memory");                                          \
  __builtin_amdgcn_sched_barrier(0);

#define BARONLY()                                                         \
  __builtin_amdgcn_s_barrier();                                           \
  asm volatile("" ::: "memory");                                          \
  __builtin_amdgcn_sched_barrier(0);

#define LOAD_BF(cur)                                                      \
  _Pragma("unroll") for (int fn = 0; fn < 4; ++fn) {                      \
    const int r = wn + fn * 16 + l15;                                     \
    bf[fn] = *reinterpret_cast<const f16x8*>(                             \
        &Bs[cur][r][(lg ^ ((r >> 1) & 3)) << 3]);                         \
  }

#define COMP_HALF(cur, T0)                                                \
  _Pragma("unroll") for (int ti = (T0); ti < (T0) + 4; ++ti) {            \
    const int r = wm + ti * 16 + l15;                                     \
    f16x8 av = *reinterpret_cast<const f16x8*>(                           \
        &As[cur][r][(lg ^ ((r >> 1) & 3)) << 3]);                         \
    _Pragma("unroll") for (int fn = 0; fn < 4; ++fn)                      \
      acc[ti][fn] = __builtin_amdgcn_mfma_f32_16x16x32_f16(               \
          av, bf[fn], acc[ti][fn], 0, 0, 0);                              \
  }

  STAGE_A(0, 0);
  STAGE_B(0, 0);
  STAGE_A(1, 1);
  STAGE_B(1, 1);

  for (int kt = 0; kt < 30; ++kt) {
    const int cur = kt & 3;
    // ---- phase A ----
    WAITBAR(4);                        // A(kt),B(kt) landed; A/B(kt+1) in flight
    STAGE_A((kt + 2) & 3, kt + 2);
    f16x8 bf[4];
    LOAD_BF(cur);
    __builtin_amdgcn_s_setprio(1);
    COMP_HALF(cur, 0);
    __builtin_amdgcn_s_setprio(0);
    // ---- phase B ----
    BARONLY();
    STAGE_B((kt + 2) & 3, kt + 2);
    __builtin_amdgcn_s_setprio(1);
    COMP_HALF(cur, 4);
    __builtin_amdgcn_s_setprio(0);
  }
  {  // kt = 30 (buf 2): A(31),B(31) may be in flight -> vmcnt(4)
    WAITBAR(4);
    f16x8 bf[4];
    LOAD_BF(2);
    __builtin_amdgcn_s_setprio(1);
    COMP_HALF(2, 0);
    __builtin_amdgcn_s_setprio(0);
    BARONLY();
    __builtin_amdgcn_s_setprio(1);
    COMP_HALF(2, 4);
    __builtin_amdgcn_s_setprio(0);
  }
  {  // kt = 31 (buf 3): drain
    WAITBAR(0);
    f16x8 bf[4];
    LOAD_BF(3);
    __builtin_amdgcn_s_setprio(1);
    COMP_HALF(3, 0);
    __builtin_amdgcn_s_setprio(0);
    BARONLY();
    __builtin_amdgcn_s_setprio(1);
    COMP_HALF(3, 4);
    __builtin_amdgcn_s_setprio(0);
  }

#pragma unroll
  for (int fm = 0; fm < 8; ++fm) {
    const int row = m0 + wm + fm * 16 + (lg << 2);
#pragma unroll
    for (int fn = 0; fn < 4; ++fn) {
      const int col = n0 + wn + fn * 16 + l15;
      const float bc = bias[col];
      f32x4 v = acc[fm][fn];
      if (F16OUT) {
        _Float16* C = (_Float16*)Cout;
#pragma unroll
        for (int j = 0; j < 4; ++j)
          C[(size_t)(row + j) * 1024 + col] = (_Float16)(v[j] + bc);
      } else {
        float* C = (float*)Cout;
#pragma unroll
        for (int j = 0; j < 4; ++j) C[(size_t)(row + j) * 1024 + col] = v[j] + bc;
      }
    }
  }
#undef STAGE_A
#undef STAGE_B
#undef WAITBAR
#undef BARONLY
#undef LOAD_BF
#undef COMP_HALF
}

// ---------------------------------------------------------------------------
// wxmax: global max of wx_k via MFMA. 512 blocks; depth-1 prefetch (R16).
// ---------------------------------------------------------------------------
__global__ __launch_bounds__(256) void wxmax_mfma_kernel(
    const _Float16* __restrict__ kproj, const float* __restrict__ proj,
    float* __restrict__ blockmax) {
  __shared__ unsigned short Xh[32][64];
  __shared__ float diags[32];  // unused (WANT_DIAG=false)
  __shared__ float redw[4];
  const int tid = threadIdx.x, blk = blockIdx.x;
  const int lane = tid & 63, w = tid >> 6;
  const int l15 = lane & 15, lg = lane >> 4;
  (void)diags;

  bf16x8 ph[2][2];
#pragma unroll
  for (int mtl = 0; mtl < 2; ++mtl)
#pragma unroll
    for (int ks = 0; ks < 2; ++ks)
      load_pfrag(proj, (2 * w + mtl) * 16 + l15, ks * 32 + lg * 8, &ph[mtl][ks]);

  float gmax = -3.4e38f;
  const int srow = tid >> 3, q8 = (tid & 7) << 3;
  const int xc = ((q8 >> 3) ^ (srow & 7)) << 3;

  f16x8 xk = *reinterpret_cast<const f16x8*>(
      kproj + (size_t)(blk * 512 + srow) * 64 + q8);

  for (int batch = 0; batch < 16; ++batch) {
    STAGE_XR(xk, false);
    f16x8 xk2;
    if (batch < 15)
      xk2 = *reinterpret_cast<const f16x8*>(
          kproj + (size_t)(blk * 512 + (batch + 1) * 32 + srow) * 64 + q8);
    __syncthreads();
    f32x4 wx[2][2];
#pragma unroll
    for (int st = 0; st < 2; ++st)
#pragma unroll
      for (int mtl = 0; mtl < 2; ++mtl) wx[st][mtl] = f32x4{0, 0, 0, 0};
    WX_COMPUTE(wx);
#pragma unroll
    for (int st = 0; st < 2; ++st)
#pragma unroll
      for (int mtl = 0; mtl < 2; ++mtl)
#pragma unroll
        for (int r = 0; r < 4; ++r) gmax = fmaxf(gmax, wx[st][mtl][r]);
    __syncthreads();
    if (batch < 15) xk = xk2;
  }
#pragma unroll
  for (int off = 32; off; off >>= 1) gmax = fmaxf(gmax, __shfl_xor(gmax, off));
  if (lane == 0) redw[w] = gmax;
  __syncthreads();
  if (tid == 0)
    blockmax[blk] = fmaxf(fmaxf(redw[0], redw[1]), fmaxf(redw[2], redw[3]));
}

__global__ __launch_bounds__(256) void maxreduce_kernel(
    const float* __restrict__ blockmax, float* __restrict__ stab, int n) {
  __shared__ float sm[256];
  float v = -3.4e38f;
  for (int i = threadIdx.x; i < n; i += 256) v = fmaxf(v, blockmax[i]);
  sm[threadIdx.x] = v;
  __syncthreads();
  for (int s = 128; s; s >>= 1) {
    if (threadIdx.x < s)
      sm[threadIdx.x] = fmaxf(sm[threadIdx.x], sm[threadIdx.x + s]);
    __syncthreads();
  }
  if (threadIdx.x == 0) *stab = sm[0];
}

// ---------------------------------------------------------------------------
// kv: kv[m][d] = sum_s phi_k[s][m] V[s][d], plus k1[m]. (R16, verified)
// ---------------------------------------------------------------------------
__global__ __launch_bounds__(256) void kv_mfma_kernel(
    const _Float16* __restrict__ kproj, const _Float16* __restrict__ vproj,
    const float* __restrict__ proj, const float* __restrict__ stabp,
    float* __restrict__ kvpartT, float* __restrict__ k1part) {
  __shared__ unsigned short Xh[32][64];
  __shared__ float Vs[32][66];
  __shared__ unsigned short phiTh[128][40];
  __shared__ float diags[32];
  const int tid = threadIdx.x, blk = blockIdx.x;
  const int c = blk & 15, bh = blk >> 4, b = bh >> 4, h = bh & 15;
  const int lane = tid & 63, w = tid >> 6;
  const int l15 = lane & 15, lg = lane >> 4;
  const float stab = *stabp;

  bf16x8 ph[2][2];
#pragma unroll
  for (int mtl = 0; mtl < 2; ++mtl)
#pragma unroll
    for (int ks = 0; ks < 2; ++ks)
      load_pfrag(proj, (2 * w + mtl) * 16 + l15, ks * 32 + lg * 8, &ph[mtl][ks]);

  f32x4 akv[2][4];
#pragma unroll
  for (int i = 0; i < 2; ++i)
#pragma unroll
    for (int j = 0; j < 4; ++j) akv[i][j] = f32x4{0, 0, 0, 0};
  float k1acc[2] = {0.f, 0.f};

  const int srow = tid >> 3, q8 = (tid & 7) << 3;
  const int xc = ((q8 >> 3) ^ (srow & 7)) << 3;

  size_t rb = (((size_t)(b * S_ + c * 256 + srow) * H_ + h)) << 6;
  f16x8 xk = *reinterpret_cast<const f16x8*>(kproj + rb + q8);
  f16x8 xv = *reinterpret_cast<const f16x8*>(vproj + rb + q8);

  for (int batch = 0; batch < 8; ++batch) {
    STAGE_XR(xk, true);
    {
#pragma unroll
      for (int j = 0; j < 8; ++j) Vs[srow][q8 + j] = (float)xv[j];
    }
    f16x8 xk2, xv2;
    if (batch < 7) {
      const size_t rb2 =
          (((size_t)(b * S_ + c * 256 + (batch + 1) * 32 + srow) * H_ + h)) << 6;
      xk2 = *reinterpret_cast<const f16x8*>(kproj + rb2 + q8);
      xv2 = *reinterpret_cast<const f16x8*>(vproj + rb2 + q8);
    }
    __syncthreads();  // bar1

    f32x4 wx[2][2];
#pragma unroll
    for (int st = 0; st < 2; ++st)
#pragma unroll
      for (int mtl = 0; mtl < 2; ++mtl) wx[st][mtl] = f32x4{0, 0, 0, 0};
    WX_COMPUTE(wx);

#pragma unroll
    for (int st = 0; st < 2; ++st)
#pragma unroll
      for (int mtl = 0; mtl < 2; ++mtl) {
        const int m = (2 * w + mtl) * 16 + l15;
        s16x4 hv;
        float psum = 0.f;
#pragma unroll
        for (int r = 0; r < 4; ++r) {
          const int s = st * 16 + lg * 4 + r;
          float p = __expf(wx[st][mtl][r] - diags[s] - stab) * CM;
          psum += p;
          hv[r] = (short)f2bf(p);
        }
        k1acc[mtl] += psum;
        *reinterpret_cast<s16x4*>(&phiTh[m][st * 16 + lg * 4]) = hv;
      }
    __syncthreads();  // bar2

    bf16x8 pah[2];
#pragma unroll
    for (int mtl = 0; mtl < 2; ++mtl)
      pah[mtl] = *reinterpret_cast<const bf16x8*>(
          &phiTh[(2 * w + mtl) * 16 + l15][lg * 8]);
#pragma unroll
    for (int dt = 0; dt < 4; ++dt) {
      bf16x8 bvh;
#pragma unroll
      for (int j = 0; j < 8; ++j)
        bvh[j] = (short)f2bf(Vs[lg * 8 + j][dt * 16 + l15]);
#pragma unroll
      for (int mtl = 0; mtl < 2; ++mtl) MFMAB(akv[mtl][dt], pah[mtl], bvh);
    }
    __syncthreads();  // bar3
    if (batch < 7) {
      xk = xk2;
      xv = xv2;
    }
  }

#pragma unroll
  for (int mtl = 0; mtl < 2; ++mtl) {
#pragma unroll
    for (int dt = 0; dt < 4; ++dt) {
      const int d = dt * 16 + l15, m0 = (2 * w + mtl) * 16 + lg * 4;
      *reinterpret_cast<f32x4*>(&kvpartT[(size_t)blk * 8192 + d * 128 + m0]) =
          akv[mtl][dt];
    }
    float kk = k1acc[mtl];
    kk += __shfl_xor(kk, 16);
    kk += __shfl_xor(kk, 32);
    if (lane < 16) k1part[blk * 128 + (2 * w + mtl) * 16 + lane] = kk;
  }
}

__global__ __launch_bounds__(256) void kvreduce_kernel(
    const float* __restrict__ kvpartT, const float* __restrict__ k1part,
    unsigned short* __restrict__ kvT, float* __restrict__ k1) {
  const int bh = blockIdx.x;
  for (int i = threadIdx.x; i < 8192; i += 256) {
    float s = 0.f;
#pragma unroll
    for (int c = 0; c < 16; ++c) s += kvpartT[(size_t)(bh * 16 + c) * 8192 + i];
    kvT[(size_t)bh * 8192 + i] = f2bf(s);
  }
  if (threadIdx.x < 128) {
    float s = 0.f;
#pragma unroll
    for (int c = 0; c < 16; ++c) s += k1part[(bh * 16 + c) * 128 + threadIdx.x];
    k1[bh * 128 + threadIdx.x] = s;
  }
}

// ---------------------------------------------------------------------------
// qkv (wave-local, barrier-free): each wave owns 16 t-rows completely.
// (R17, verified)
// ---------------------------------------------------------------------------
__global__ __launch_bounds__(256) void qkv_wave_kernel(
    const _Float16* __restrict__ qproj, const unsigned short* __restrict__ kvT,
    const float* __restrict__ k1g, const float* __restrict__ proj,
    _Float16* __restrict__ outh) {
  __shared__ unsigned short Pl[128][64];
  __shared__ unsigned short Kl[64][128];
  __shared__ unsigned short Phw[4][16][128];
  __shared__ float k1s[128];
  __shared__ float dgw[4][16];
  __shared__ float dnw[4][16];
  const int tid = threadIdx.x, blk = blockIdx.x;
  const int ch = blk & 31, bh = blk >> 5, b = bh >> 4, h = bh & 15;
  const int lane = tid & 63, w = tid >> 6;
  const int l15 = lane & 15, lg = lane >> 4;

  {
    const int r = tid >> 1;
    const int cb = (tid & 1) << 2;
#pragma unroll
    for (int j = 0; j < 4; ++j) {
      const int ck = cb + j;
      float4 a = *reinterpret_cast<const float4*>(proj + r * 64 + ck * 8);
      float4 bq = *reinterpret_cast<const float4*>(proj + r * 64 + ck * 8 + 4);
      float v[8] = {a.x, a.y, a.z, a.w, bq.x, bq.y, bq.z, bq.w};
      u16x8 hh;
#pragma unroll
      for (int q = 0; q < 8; ++q) hh[q] = f2bf(v[q]);
      *reinterpret_cast<u16x8*>(&Pl[r][(ck ^ (r & 7)) << 3]) = hh;
    }
    const int d = tid >> 2;
    const int kb = (tid & 3) << 2;
#pragma unroll
    for (int j = 0; j < 4; ++j) {
      const int ck = kb + j;
      u16x8 kk = *reinterpret_cast<const u16x8*>(
          kvT + (size_t)bh * 8192 + d * 128 + ck * 8);
      *reinterpret_cast<u16x8*>(&Kl[d][(ck ^ (d & 7)) << 3]) = kk;
    }
    if (tid < 128) k1s[tid] = k1g[bh * 128 + tid];
  }
  __syncthreads();  // the ONLY barrier

  float k1v[8];
#pragma unroll
  for (int mt = 0; mt < 8; ++mt) k1v[mt] = k1s[mt * 16 + l15];

#pragma unroll
  for (int it = 0; it < 2; ++it) {
    const int t0 = ch * 128 + w * 32 + it * 16;
    const size_t xrow = (((size_t)(b * S_ + t0 + l15) * H_ + h)) << 6;
    f16x8 x0 = *reinterpret_cast<const f16x8*>(qproj + xrow + lg * 8);
    f16x8 x1 = *reinterpret_cast<const f16x8*>(qproj + xrow + 32 + lg * 8);
    bf16x8 xb0, xb1;
    float sq = 0.f;
#pragma unroll
    for (int j = 0; j < 8; ++j) {
      float v0 = (float)x0[j] * SCALE_X;
      float v1 = (float)x1[j] * SCALE_X;
      sq += v0 * v0 + v1 * v1;
      xb0[j] = (short)f2bf(v0);
      xb1[j] = (short)f2bf(v1);
    }
    sq += __shfl_xor(sq, 16);
    sq += __shfl_xor(sq, 32);
    if (lg == 0) dgw[w][l15] = 0.5f * sq;

    f32x4 wxa[8];
#pragma unroll
    for (int mt = 0; mt < 8; ++mt) {
      wxa[mt] = f32x4{0.f, 0.f, 0.f, 0.f};
      bf16x8 p0 = *reinterpret_cast<const bf16x8*>(
          &Pl[mt * 16 + l15][((lg) ^ (l15 & 7)) << 3]);
      bf16x8 p1 = *reinterpret_cast<const bf16x8*>(
          &Pl[mt * 16 + l15][((4 + lg) ^ (l15 & 7)) << 3]);
      MFMAB(wxa[mt], xb0, p0);
      MFMAB(wxa[mt], xb1, p1);
    }

    float rmx[4];
#pragma unroll
    for (int r = 0; r < 4; ++r) {
      float v = wxa[0][r];
#pragma unroll
      for (int mt = 1; mt < 8; ++mt) v = fmaxf(v, wxa[mt][r]);
      v = fmaxf(v, __shfl_xor(v, 1));
      v = fmaxf(v, __shfl_xor(v, 2));
      v = fmaxf(v, __shfl_xor(v, 4));
      v = fmaxf(v, __shfl_xor(v, 8));
      rmx[r] = v;
    }
    float den[4] = {0.f, 0.f, 0.f, 0.f};
#pragma unroll
    for (int r = 0; r < 4; ++r) {
      const int trow = lg * 4 + r;
      const float off = rmx[r] + dgw[w][trow];
#pragma unroll
      for (int mt = 0; mt < 8; ++mt) {
        const int m = mt * 16 + l15;
        float p = __expf(wxa[mt][r] - off) * CM;
        den[r] += p * k1v[mt];
        Phw[w][trow][((((m >> 3)) ^ (trow & 7)) << 3) | (m & 7)] = f2bf(p);
      }
    }
#pragma unroll
    for (int r = 0; r < 4; ++r) {
      float v = den[r];
      v += __shfl_xor(v, 1);
      v += __shfl_xor(v, 2);
      v += __shfl_xor(v, 4);
      v += __shfl_xor(v, 8);
      if (l15 == 0) dnw[w][lg * 4 + r] = v;
    }

    const float dens = 1.f / (dnw[w][l15] + 1e-6f);
#pragma unroll
    for (int dt = 0; dt < 4; ++dt) {
      f32x4 od = {0.f, 0.f, 0.f, 0.f};
#pragma unroll
      for (int ks = 0; ks < 4; ++ks) {
        bf16x8 ka = *reinterpret_cast<const bf16x8*>(
            &Kl[dt * 16 + l15][((ks * 4 + lg) ^ (l15 & 7)) << 3]);
        bf16x8 bp = *reinterpret_cast<const bf16x8*>(
            &Phw[w][l15][((ks * 4 + lg) ^ (l15 & 7)) << 3]);
        MFMAB(od, ka, bp);
      }
      f16x4 o;
#pragma unroll
      for (int j = 0; j < 4; ++j) o[j] = (_Float16)(od[j] * dens);
      *reinterpret_cast<f16x4*>(
          &outh[(size_t)(b * S_ + t0 + l15) * 1024 + h * 64 + dt * 16 +
                lg * 4]) = o;
    }
  }
}

// ---------------------------------------------------------------------------
extern "C" void kernel_launch(void* const* d_in, const int* in_sizes, int n_in,
                              void* d_out, int out_size, void* d_ws,
                              size_t ws_size, hipStream_t stream) {
  const float* query = (const float*)d_in[0];
  const float* value = (const float*)d_in[1];
  const float* key   = (const float*)d_in[2];
  const float* Wq = (const float*)d_in[3];
  const float* bq = (const float*)d_in[4];
  const float* Wk = (const float*)d_in[5];
  const float* bk = (const float*)d_in[6];
  const float* Wv = (const float*)d_in[7];
  const float* bv = (const float*)d_in[8];
  const float* Wo = (const float*)d_in[9];
  const float* bo = (const float*)d_in[10];
  const float* proj = (const float*)d_in[11];
  float* out = (float*)d_out;
  float* ws = (float*)d_ws;

  _Float16* KP16 = (_Float16*)(ws + OFF_A);   // kproj then qproj (fp16)
  _Float16* VP16 = (_Float16*)(ws + OFF_B);   // vproj (fp16)
  _Float16* WT = (_Float16*)(ws + OFF_X);
  float* K1P = ws + OFF_X;                    // k1part (WT dead at kv time)
  unsigned short* KVT = (unsigned short*)(ws + OFF_KV);
  float* K1 = ws + OFF_K1;
  float* BMX = ws + OFF_BM;
  float* ST = ws + OFF_ST;
  _Float16* X16 = (_Float16*)(ws + OFF_A16);  // GEMM A staging
  float* KVPT = ws + OFF_A16;                 // kv partials (staging dead)

  dim3 gw(32, 32);

  // 1. k_proj (fp16)
  cvt_f16_kernel<<<2048, 256, 0, stream>>>(key, X16);
  wt_f16_kernel<<<gw, 256, 0, stream>>>(Wk, WT);
  gemm_lds<1><<<256, 512, 0, stream>>>(X16, WT, bk, KP16);
  // 2. stab (reference global max wx_k)
  wxmax_mfma_kernel<<<512, 256, 0, stream>>>(KP16, proj, BMX);
  maxreduce_kernel<<<1, 256, 0, stream>>>(BMX, ST, 512);
  // 3. v_proj (fp16)
  cvt_f16_kernel<<<2048, 256, 0, stream>>>(value, X16);
  wt_f16_kernel<<<gw, 256, 0, stream>>>(Wv, WT);
  gemm_lds<1><<<256, 512, 0, stream>>>(X16, WT, bv, VP16);
  // 4. kv / k1 (KVPT aliases X16 staging — dead; K1P aliases WT — dead)
  kv_mfma_kernel<<<1024, 256, 0, stream>>>(KP16, VP16, proj, ST, KVPT, K1P);
  kvreduce_kernel<<<64, 256, 0, stream>>>(KVPT, K1P, KVT, K1);
  // 5. q_proj (KVPT dead after reduce; kproj dead after kv)
  cvt_f16_kernel<<<2048, 256, 0, stream>>>(query, X16);
  wt_f16_kernel<<<gw, 256, 0, stream>>>(Wq, WT);
  gemm_lds<1><<<256, 512, 0, stream>>>(X16, WT, bq, KP16);
  // 6. out_h -> X16 as fp16 (query staging dead after q_proj gemm)
  qkv_wave_kernel<<<2048, 256, 0, stream>>>(KP16, KVT, K1, proj, X16);
  // 7. output projection (f32 out)
  wt_f16_kernel<<<gw, 256, 0, stream>>>(Wo, WT);
  gemm_lds<0><<<256, 512, 0, stream>>>(X16, WT, bo, out);
}

// Round 22
// 302.017 us; speedup vs baseline: 1.1759x; 1.1759x over previous
//
#include <hip/hip_runtime.h>
#include <hip/hip_bf16.h>

// Performer (FAVOR+) forward. Round 22: full revert to R17 (verified best,
// 301.5us, absmax 9.77e-3). R18-R21 GEMM experiments (B-in-registers, XCD
// swizzle, 32x32 MFMA, 2-phase split) all regressed and are reverted.
// Structure: fp16 cvt + wt -> pipelined 256x256 fp16 GEMM (4-deep LDS,
// counted vmcnt(8)) -> MFMA wxmax/kv (depth-1 prefetch) -> barrier-free
// wave-local qkv -> final GEMM.
// B=4, S=4096, D=1024, H=16, K=64, M=128.

#define B_  4
#define S_  4096
#define H_  16

#define SCALE_X 0.3535533905932738f     // 64^-0.25
#define CM      0.08838834764831845f    // 128^-0.5

typedef __attribute__((ext_vector_type(8))) short bf16x8;
typedef __attribute__((ext_vector_type(4))) short s16x4;
typedef __attribute__((ext_vector_type(8))) unsigned short u16x8;
typedef __attribute__((ext_vector_type(8))) _Float16 f16x8;
typedef __attribute__((ext_vector_type(4))) _Float16 f16x4;
typedef __attribute__((ext_vector_type(4))) float f32x4;

// ---- ws layout (float units) ----
#define OFF_A    ((size_t)0)          // kproj16 then qproj16 (fp16, 32MB)
#define OFF_B    ((size_t)16777216)   // vproj16 (fp16)
#define OFF_X    ((size_t)33554432)   // union: WT fp16 / k1part(131072)
#define OFF_KV   ((size_t)37814272)   // kvT bf16: 524288 ush
#define OFF_K1   ((size_t)38338560)   // 64*128 f32
#define OFF_BM   ((size_t)38346752)   // 512 block maxes
#define OFF_ST   ((size_t)38347264)   // stab scalar
#define OFF_A16  ((size_t)38347776)   // 8388608 f32: GEMM A staging / kvpartT
// total 46736384 f32 = 186.9 MB

__device__ __forceinline__ unsigned short f2bf(float x) {
  union { __hip_bfloat16 b; unsigned short u; } c;
  c.b = __float2bfloat16(x);
  return c.u;
}

#define MFMAB(ACC, A, B)                                               \
  ACC = __builtin_amdgcn_mfma_f32_16x16x32_bf16(A, B, ACC, 0, 0, 0)

#define GLDS(GP, LP)                                                  \
  __builtin_amdgcn_global_load_lds(                                   \
      (const __attribute__((address_space(1))) unsigned int*)(GP),    \
      (__attribute__((address_space(3))) unsigned int*)(LP), 16, 0, 0)

// load P-operand fragment (B for wx): lane supplies P[m][kb..kb+7] as bf16
__device__ __forceinline__ void load_pfrag(const float* __restrict__ proj, int m,
                                           int kb, bf16x8* ph) {
  const float* p = proj + m * 64 + kb;
  float4 a = *reinterpret_cast<const float4*>(p);
  float4 b = *reinterpret_cast<const float4*>(p + 4);
  float v[8] = {a.x, a.y, a.z, a.w, b.x, b.y, b.z, b.w};
  bf16x8 h;
#pragma unroll
  for (int j = 0; j < 8; ++j) h[j] = (short)f2bf(v[j]);
  *ph = h;
}

// Stage one X row-chunk FROM REGISTERS: scale, bf16, chunk-XOR LDS write.
#define STAGE_XR(XV, WANT_DIAG)                                           \
  {                                                                       \
    f16x8 xv_ = (XV);                                                     \
    u16x8 hh_;                                                            \
    float sq_ = 0.f;                                                      \
    _Pragma("unroll") for (int j = 0; j < 8; ++j) {                       \
      float vf_ = (float)xv_[j] * SCALE_X;                                \
      sq_ += vf_ * vf_;                                                   \
      hh_[j] = f2bf(vf_);                                                 \
    }                                                                     \
    *reinterpret_cast<u16x8*>(&Xh[srow][xc]) = hh_;                       \
    if (WANT_DIAG) {                                                      \
      sq_ += __shfl_xor(sq_, 1);                                          \
      sq_ += __shfl_xor(sq_, 2);                                          \
      sq_ += __shfl_xor(sq_, 4);                                          \
      if ((tid & 7) == 0) diags[srow] = 0.5f * sq_;                       \
    }                                                                     \
  }

// wx MFMA block: 2 st x 2 ks x 2 mtl, single bf16 MFMA each.
#define WX_COMPUTE(WX)                                                       \
  _Pragma("unroll") for (int st_ = 0; st_ < 2; ++st_)                        \
  _Pragma("unroll") for (int ks_ = 0; ks_ < 2; ++ks_) {                      \
    const int rr_ = st_ * 16 + l15;                                          \
    const int cc_ = ((ks_ * 4 + lg) ^ (l15 & 7)) << 3;                       \
    bf16x8 xh_ = *reinterpret_cast<const bf16x8*>(&Xh[rr_][cc_]);            \
    _Pragma("unroll") for (int mtl_ = 0; mtl_ < 2; ++mtl_)                   \
        MFMAB(WX[st_][mtl_], xh_, ph[mtl_][ks_]);                            \
  }

// ---------------------------------------------------------------------------
// f32 -> fp16 conversion pass (16777216 elements).
// ---------------------------------------------------------------------------
__global__ __launch_bounds__(256) void cvt_f16_kernel(
    const float* __restrict__ in, _Float16* __restrict__ out) {
  const size_t stride = (size_t)gridDim.x * 256 * 8;
  for (size_t i = ((size_t)blockIdx.x * 256 + threadIdx.x) * 8; i < 16777216UL;
       i += stride) {
    float4 a = *reinterpret_cast<const float4*>(in + i);
    float4 b = *reinterpret_cast<const float4*>(in + i + 4);
    f16x8 h;
    h[0] = (_Float16)a.x; h[1] = (_Float16)a.y;
    h[2] = (_Float16)a.z; h[3] = (_Float16)a.w;
    h[4] = (_Float16)b.x; h[5] = (_Float16)b.y;
    h[6] = (_Float16)b.z; h[7] = (_Float16)b.w;
    *reinterpret_cast<f16x8*>(out + i) = h;
  }
}

// ---------------------------------------------------------------------------
// Weight transform: W[1024 k][1024 n] f32 -> WT [n][k] fp16.
// ---------------------------------------------------------------------------
__global__ __launch_bounds__(256) void wt_f16_kernel(
    const float* __restrict__ W, _Float16* __restrict__ T) {
  __shared__ float t[32][33];
  const int tx = threadIdx.x & 31, ty = threadIdx.x >> 5;
  const int k0 = blockIdx.x * 32, n0 = blockIdx.y * 32;
#pragma unroll
  for (int i = 0; i < 4; ++i)
    t[ty + 8 * i][tx] = W[(size_t)(k0 + ty + 8 * i) * 1024 + n0 + tx];
  __syncthreads();
#pragma unroll
  for (int i = 0; i < 4; ++i)
    T[(size_t)(n0 + ty + 8 * i) * 1024 + k0 + tx] = (_Float16)t[tx][ty + 8 * i];
}

// ---------------------------------------------------------------------------
// Pipelined fp16 GEMM, 256x256 tile (R15/R17 verified): 512 threads, BK=32,
// 4-deep LDS, issue-ahead 2, counted vmcnt(8).
// ---------------------------------------------------------------------------
template <int F16OUT>
__global__ __launch_bounds__(512) void gemm_lds(
    const _Float16* __restrict__ A16, const _Float16* __restrict__ BT,
    const float* __restrict__ bias, void* __restrict__ Cout) {
  __shared__ _Float16 As[4][256][32];
  __shared__ _Float16 Bs[4][256][32];
  const int tid = threadIdx.x;
  const int bid = blockIdx.x;
  const int m0 = (bid & 63) << 8;
  const int n0 = (bid >> 6) << 8;
  const int wave = tid >> 6, lane = tid & 63;
  const int wm = (wave >> 2) << 7;
  const int wn = (wave & 3) << 6;
  const int l15 = lane & 15, lg = lane >> 4;

  const int rlo = tid >> 2;
  const int cg = ((tid & 3) ^ ((rlo >> 1) & 3)) << 3;
  const int wqbase = wave << 10;

  const _Float16* pa = A16 + (size_t)(m0 + rlo) * 1024 + cg;
  const _Float16* pb = BT + (size_t)(n0 + rlo) * 1024 + cg;

  f32x4 acc[8][4];
#pragma unroll
  for (int i = 0; i < 8; ++i)
#pragma unroll
    for (int j = 0; j < 4; ++j) acc[i][j] = f32x4{0.f, 0.f, 0.f, 0.f};

#define STAGE_T(nb, kt)                                                   \
  {                                                                       \
    char* la = (char*)&As[nb][0][0] + wqbase;                             \
    char* lb = (char*)&Bs[nb][0][0] + wqbase;                             \
    GLDS(pa + (kt) * 32, la);                                             \
    GLDS(pa + (kt) * 32 + 131072, la + 8192);                             \
    GLDS(pb + (kt) * 32, lb);                                             \
    GLDS(pb + (kt) * 32 + 131072, lb + 8192);                             \
  }

#define PIPE_BAR(N)                                                       \
  asm volatile("s_waitcnt vmcnt(" #N ")" ::: "memory");                   \
  __builtin_amdgcn_s_barrier();                                           \
  asm volatile("" ::: "memory");                                          \
  __builtin_amdgcn_sched_barrier(0);

#define COMPUTE(cur)                                                      \
  {                                                                       \
    f16x8 bf[4];                                                          \
    _Pragma("unroll") for (int fn = 0; fn < 4; ++fn) {                    \
      const int r = wn + fn * 16 + l15;                                   \
      bf[fn] = *reinterpret_cast<const f16x8*>(                           \
          &Bs[cur][r][(lg ^ ((r >> 1) & 3)) << 3]);                       \
    }                                                                     \
    _Pragma("unroll") for (int fm = 0; fm < 8; ++fm) {                    \
      const int r = wm + fm * 16 + l15;                                   \
      f16x8 av = *reinterpret_cast<const f16x8*>(                         \
          &As[cur][r][(lg ^ ((r >> 1) & 3)) << 3]);                       \
      _Pragma("unroll") for (int fn = 0; fn < 4; ++fn)                    \
        acc[fm][fn] = __builtin_amdgcn_mfma_f32_16x16x32_f16(             \
            av, bf[fn], acc[fm][fn], 0, 0, 0);                            \
    }                                                                     \
  }

  STAGE_T(0, 0);
  STAGE_T(1, 1);

  for (int kt = 0; kt < 30; ++kt) {
    STAGE_T((kt + 2) & 3, kt + 2);
    PIPE_BAR(8);
    COMPUTE(kt & 3);
  }
  PIPE_BAR(4);
  COMPUTE(2);  // kt = 30
  PIPE_BAR(0);
  COMPUTE(3);  // kt = 31

#pragma unroll
  for (int fm = 0; fm < 8; ++fm) {
    const int row = m0 + wm + fm * 16 + (lg << 2);
#pragma unroll
    for (int fn = 0; fn < 4; ++fn) {
      const int col = n0 + wn + fn * 16 + l15;
      const float bc = bias[col];
      f32x4 v = acc[fm][fn];
      if (F16OUT) {
        _Float16* C = (_Float16*)Cout;
#pragma unroll
        for (int j = 0; j < 4; ++j)
          C[(size_t)(row + j) * 1024 + col] = (_Float16)(v[j] + bc);
      } else {
        float* C = (float*)Cout;
#pragma unroll
        for (int j = 0; j < 4; ++j) C[(size_t)(row + j) * 1024 + col] = v[j] + bc;
      }
    }
  }
#undef STAGE_T
#undef PIPE_BAR
#undef COMPUTE
}

// ---------------------------------------------------------------------------
// wxmax: global max of wx_k via MFMA. 512 blocks; depth-1 prefetch (R16).
// ---------------------------------------------------------------------------
__global__ __launch_bounds__(256) void wxmax_mfma_kernel(
    const _Float16* __restrict__ kproj, const float* __restrict__ proj,
    float* __restrict__ blockmax) {
  __shared__ unsigned short Xh[32][64];
  __shared__ float diags[32];  // unused (WANT_DIAG=false)
  __shared__ float redw[4];
  const int tid = threadIdx.x, blk = blockIdx.x;
  const int lane = tid & 63, w = tid >> 6;
  const int l15 = lane & 15, lg = lane >> 4;
  (void)diags;

  bf16x8 ph[2][2];
#pragma unroll
  for (int mtl = 0; mtl < 2; ++mtl)
#pragma unroll
    for (int ks = 0; ks < 2; ++ks)
      load_pfrag(proj, (2 * w + mtl) * 16 + l15, ks * 32 + lg * 8, &ph[mtl][ks]);

  float gmax = -3.4e38f;
  const int srow = tid >> 3, q8 = (tid & 7) << 3;
  const int xc = ((q8 >> 3) ^ (srow & 7)) << 3;

  f16x8 xk = *reinterpret_cast<const f16x8*>(
      kproj + (size_t)(blk * 512 + srow) * 64 + q8);

  for (int batch = 0; batch < 16; ++batch) {
    STAGE_XR(xk, false);
    f16x8 xk2;
    if (batch < 15)
      xk2 = *reinterpret_cast<const f16x8*>(
          kproj + (size_t)(blk * 512 + (batch + 1) * 32 + srow) * 64 + q8);
    __syncthreads();
    f32x4 wx[2][2];
#pragma unroll
    for (int st = 0; st < 2; ++st)
#pragma unroll
      for (int mtl = 0; mtl < 2; ++mtl) wx[st][mtl] = f32x4{0, 0, 0, 0};
    WX_COMPUTE(wx);
#pragma unroll
    for (int st = 0; st < 2; ++st)
#pragma unroll
      for (int mtl = 0; mtl < 2; ++mtl)
#pragma unroll
        for (int r = 0; r < 4; ++r) gmax = fmaxf(gmax, wx[st][mtl][r]);
    __syncthreads();
    if (batch < 15) xk = xk2;
  }
#pragma unroll
  for (int off = 32; off; off >>= 1) gmax = fmaxf(gmax, __shfl_xor(gmax, off));
  if (lane == 0) redw[w] = gmax;
  __syncthreads();
  if (tid == 0)
    blockmax[blk] = fmaxf(fmaxf(redw[0], redw[1]), fmaxf(redw[2], redw[3]));
}

__global__ __launch_bounds__(256) void maxreduce_kernel(
    const float* __restrict__ blockmax, float* __restrict__ stab, int n) {
  __shared__ float sm[256];
  float v = -3.4e38f;
  for (int i = threadIdx.x; i < n; i += 256) v = fmaxf(v, blockmax[i]);
  sm[threadIdx.x] = v;
  __syncthreads();
  for (int s = 128; s; s >>= 1) {
    if (threadIdx.x < s)
      sm[threadIdx.x] = fmaxf(sm[threadIdx.x], sm[threadIdx.x + s]);
    __syncthreads();
  }
  if (threadIdx.x == 0) *stab = sm[0];
}

// ---------------------------------------------------------------------------
// kv: kv[m][d] = sum_s phi_k[s][m] V[s][d], plus k1[m]. (R16, verified)
// ---------------------------------------------------------------------------
__global__ __launch_bounds__(256) void kv_mfma_kernel(
    const _Float16* __restrict__ kproj, const _Float16* __restrict__ vproj,
    const float* __restrict__ proj, const float* __restrict__ stabp,
    float* __restrict__ kvpartT, float* __restrict__ k1part) {
  __shared__ unsigned short Xh[32][64];
  __shared__ float Vs[32][66];
  __shared__ unsigned short phiTh[128][40];
  __shared__ float diags[32];
  const int tid = threadIdx.x, blk = blockIdx.x;
  const int c = blk & 15, bh = blk >> 4, b = bh >> 4, h = bh & 15;
  const int lane = tid & 63, w = tid >> 6;
  const int l15 = lane & 15, lg = lane >> 4;
  const float stab = *stabp;

  bf16x8 ph[2][2];
#pragma unroll
  for (int mtl = 0; mtl < 2; ++mtl)
#pragma unroll
    for (int ks = 0; ks < 2; ++ks)
      load_pfrag(proj, (2 * w + mtl) * 16 + l15, ks * 32 + lg * 8, &ph[mtl][ks]);

  f32x4 akv[2][4];
#pragma unroll
  for (int i = 0; i < 2; ++i)
#pragma unroll
    for (int j = 0; j < 4; ++j) akv[i][j] = f32x4{0, 0, 0, 0};
  float k1acc[2] = {0.f, 0.f};

  const int srow = tid >> 3, q8 = (tid & 7) << 3;
  const int xc = ((q8 >> 3) ^ (srow & 7)) << 3;

  size_t rb = (((size_t)(b * S_ + c * 256 + srow) * H_ + h)) << 6;
  f16x8 xk = *reinterpret_cast<const f16x8*>(kproj + rb + q8);
  f16x8 xv = *reinterpret_cast<const f16x8*>(vproj + rb + q8);

  for (int batch = 0; batch < 8; ++batch) {
    STAGE_XR(xk, true);
    {
#pragma unroll
      for (int j = 0; j < 8; ++j) Vs[srow][q8 + j] = (float)xv[j];
    }
    f16x8 xk2, xv2;
    if (batch < 7) {
      const size_t rb2 =
          (((size_t)(b * S_ + c * 256 + (batch + 1) * 32 + srow) * H_ + h)) << 6;
      xk2 = *reinterpret_cast<const f16x8*>(kproj + rb2 + q8);
      xv2 = *reinterpret_cast<const f16x8*>(vproj + rb2 + q8);
    }
    __syncthreads();  // bar1

    f32x4 wx[2][2];
#pragma unroll
    for (int st = 0; st < 2; ++st)
#pragma unroll
      for (int mtl = 0; mtl < 2; ++mtl) wx[st][mtl] = f32x4{0, 0, 0, 0};
    WX_COMPUTE(wx);

#pragma unroll
    for (int st = 0; st < 2; ++st)
#pragma unroll
      for (int mtl = 0; mtl < 2; ++mtl) {
        const int m = (2 * w + mtl) * 16 + l15;
        s16x4 hv;
        float psum = 0.f;
#pragma unroll
        for (int r = 0; r < 4; ++r) {
          const int s = st * 16 + lg * 4 + r;
          float p = __expf(wx[st][mtl][r] - diags[s] - stab) * CM;
          psum += p;
          hv[r] = (short)f2bf(p);
        }
        k1acc[mtl] += psum;
        *reinterpret_cast<s16x4*>(&phiTh[m][st * 16 + lg * 4]) = hv;
      }
    __syncthreads();  // bar2

    bf16x8 pah[2];
#pragma unroll
    for (int mtl = 0; mtl < 2; ++mtl)
      pah[mtl] = *reinterpret_cast<const bf16x8*>(
          &phiTh[(2 * w + mtl) * 16 + l15][lg * 8]);
#pragma unroll
    for (int dt = 0; dt < 4; ++dt) {
      bf16x8 bvh;
#pragma unroll
      for (int j = 0; j < 8; ++j)
        bvh[j] = (short)f2bf(Vs[lg * 8 + j][dt * 16 + l15]);
#pragma unroll
      for (int mtl = 0; mtl < 2; ++mtl) MFMAB(akv[mtl][dt], pah[mtl], bvh);
    }
    __syncthreads();  // bar3
    if (batch < 7) {
      xk = xk2;
      xv = xv2;
    }
  }

#pragma unroll
  for (int mtl = 0; mtl < 2; ++mtl) {
#pragma unroll
    for (int dt = 0; dt < 4; ++dt) {
      const int d = dt * 16 + l15, m0 = (2 * w + mtl) * 16 + lg * 4;
      *reinterpret_cast<f32x4*>(&kvpartT[(size_t)blk * 8192 + d * 128 + m0]) =
          akv[mtl][dt];
    }
    float kk = k1acc[mtl];
    kk += __shfl_xor(kk, 16);
    kk += __shfl_xor(kk, 32);
    if (lane < 16) k1part[blk * 128 + (2 * w + mtl) * 16 + lane] = kk;
  }
}

__global__ __launch_bounds__(256) void kvreduce_kernel(
    const float* __restrict__ kvpartT, const float* __restrict__ k1part,
    unsigned short* __restrict__ kvT, float* __restrict__ k1) {
  const int bh = blockIdx.x;
  for (int i = threadIdx.x; i < 8192; i += 256) {
    float s = 0.f;
#pragma unroll
    for (int c = 0; c < 16; ++c) s += kvpartT[(size_t)(bh * 16 + c) * 8192 + i];
    kvT[(size_t)bh * 8192 + i] = f2bf(s);
  }
  if (threadIdx.x < 128) {
    float s = 0.f;
#pragma unroll
    for (int c = 0; c < 16; ++c) s += k1part[(bh * 16 + c) * 128 + threadIdx.x];
    k1[bh * 128 + threadIdx.x] = s;
  }
}

// ---------------------------------------------------------------------------
// qkv (wave-local, barrier-free): each wave owns 16 t-rows completely.
// (R17, verified)
// ---------------------------------------------------------------------------
__global__ __launch_bounds__(256) void qkv_wave_kernel(
    const _Float16* __restrict__ qproj, const unsigned short* __restrict__ kvT,
    const float* __restrict__ k1g, const float* __restrict__ proj,
    _Float16* __restrict__ outh) {
  __shared__ unsigned short Pl[128][64];
  __shared__ unsigned short Kl[64][128];
  __shared__ unsigned short Phw[4][16][128];
  __shared__ float k1s[128];
  __shared__ float dgw[4][16];
  __shared__ float dnw[4][16];
  const int tid = threadIdx.x, blk = blockIdx.x;
  const int ch = blk & 31, bh = blk >> 5, b = bh >> 4, h = bh & 15;
  const int lane = tid & 63, w = tid >> 6;
  const int l15 = lane & 15, lg = lane >> 4;

  {
    const int r = tid >> 1;
    const int cb = (tid & 1) << 2;
#pragma unroll
    for (int j = 0; j < 4; ++j) {
      const int ck = cb + j;
      float4 a = *reinterpret_cast<const float4*>(proj + r * 64 + ck * 8);
      float4 bq = *reinterpret_cast<const float4*>(proj + r * 64 + ck * 8 + 4);
      float v[8] = {a.x, a.y, a.z, a.w, bq.x, bq.y, bq.z, bq.w};
      u16x8 hh;
#pragma unroll
      for (int q = 0; q < 8; ++q) hh[q] = f2bf(v[q]);
      *reinterpret_cast<u16x8*>(&Pl[r][(ck ^ (r & 7)) << 3]) = hh;
    }
    const int d = tid >> 2;
    const int kb = (tid & 3) << 2;
#pragma unroll
    for (int j = 0; j < 4; ++j) {
      const int ck = kb + j;
      u16x8 kk = *reinterpret_cast<const u16x8*>(
          kvT + (size_t)bh * 8192 + d * 128 + ck * 8);
      *reinterpret_cast<u16x8*>(&Kl[d][(ck ^ (d & 7)) << 3]) = kk;
    }
    if (tid < 128) k1s[tid] = k1g[bh * 128 + tid];
  }
  __syncthreads();  // the ONLY barrier

  float k1v[8];
#pragma unroll
  for (int mt = 0; mt < 8; ++mt) k1v[mt] = k1s[mt * 16 + l15];

#pragma unroll
  for (int it = 0; it < 2; ++it) {
    const int t0 = ch * 128 + w * 32 + it * 16;
    const size_t xrow = (((size_t)(b * S_ + t0 + l15) * H_ + h)) << 6;
    f16x8 x0 = *reinterpret_cast<const f16x8*>(qproj + xrow + lg * 8);
    f16x8 x1 = *reinterpret_cast<const f16x8*>(qproj + xrow + 32 + lg * 8);
    bf16x8 xb0, xb1;
    float sq = 0.f;
#pragma unroll
    for (int j = 0; j < 8; ++j) {
      float v0 = (float)x0[j] * SCALE_X;
      float v1 = (float)x1[j] * SCALE_X;
      sq += v0 * v0 + v1 * v1;
      xb0[j] = (short)f2bf(v0);
      xb1[j] = (short)f2bf(v1);
    }
    sq += __shfl_xor(sq, 16);
    sq += __shfl_xor(sq, 32);
    if (lg == 0) dgw[w][l15] = 0.5f * sq;

    f32x4 wxa[8];
#pragma unroll
    for (int mt = 0; mt < 8; ++mt) {
      wxa[mt] = f32x4{0.f, 0.f, 0.f, 0.f};
      bf16x8 p0 = *reinterpret_cast<const bf16x8*>(
          &Pl[mt * 16 + l15][((lg) ^ (l15 & 7)) << 3]);
      bf16x8 p1 = *reinterpret_cast<const bf16x8*>(
          &Pl[mt * 16 + l15][((4 + lg) ^ (l15 & 7)) << 3]);
      MFMAB(wxa[mt], xb0, p0);
      MFMAB(wxa[mt], xb1, p1);
    }

    float rmx[4];
#pragma unroll
    for (int r = 0; r < 4; ++r) {
      float v = wxa[0][r];
#pragma unroll
      for (int mt = 1; mt < 8; ++mt) v = fmaxf(v, wxa[mt][r]);
      v = fmaxf(v, __shfl_xor(v, 1));
      v = fmaxf(v, __shfl_xor(v, 2));
      v = fmaxf(v, __shfl_xor(v, 4));
      v = fmaxf(v, __shfl_xor(v, 8));
      rmx[r] = v;
    }
    float den[4] = {0.f, 0.f, 0.f, 0.f};
#pragma unroll
    for (int r = 0; r < 4; ++r) {
      const int trow = lg * 4 + r;
      const float off = rmx[r] + dgw[w][trow];
#pragma unroll
      for (int mt = 0; mt < 8; ++mt) {
        const int m = mt * 16 + l15;
        float p = __expf(wxa[mt][r] - off) * CM;
        den[r] += p * k1v[mt];
        Phw[w][trow][((((m >> 3)) ^ (trow & 7)) << 3) | (m & 7)] = f2bf(p);
      }
    }
#pragma unroll
    for (int r = 0; r < 4; ++r) {
      float v = den[r];
      v += __shfl_xor(v, 1);
      v += __shfl_xor(v, 2);
      v += __shfl_xor(v, 4);
      v += __shfl_xor(v, 8);
      if (l15 == 0) dnw[w][lg * 4 + r] = v;
    }

    const float dens = 1.f / (dnw[w][l15] + 1e-6f);
#pragma unroll
    for (int dt = 0; dt < 4; ++dt) {
      f32x4 od = {0.f, 0.f, 0.f, 0.f};
#pragma unroll
      for (int ks = 0; ks < 4; ++ks) {
        bf16x8 ka = *reinterpret_cast<const bf16x8*>(
            &Kl[dt * 16 + l15][((ks * 4 + lg) ^ (l15 & 7)) << 3]);
        bf16x8 bp = *reinterpret_cast<const bf16x8*>(
            &Phw[w][l15][((ks * 4 + lg) ^ (l15 & 7)) << 3]);
        MFMAB(od, ka, bp);
      }
      f16x4 o;
#pragma unroll
      for (int j = 0; j < 4; ++j) o[j] = (_Float16)(od[j] * dens);
      *reinterpret_cast<f16x4*>(
          &outh[(size_t)(b * S_ + t0 + l15) * 1024 + h * 64 + dt * 16 +
                lg * 4]) = o;
    }
  }
}

// ---------------------------------------------------------------------------
extern "C" void kernel_launch(void* const* d_in, const int* in_sizes, int n_in,
                              void* d_out, int out_size, void* d_ws,
                              size_t ws_size, hipStream_t stream) {
  const float* query = (const float*)d_in[0];
  const float* value = (const float*)d_in[1];
  const float* key   = (const float*)d_in[2];
  const float* Wq = (const float*)d_in[3];
  const float* bq = (const float*)d_in[4];
  const float* Wk = (const float*)d_in[5];
  const float* bk = (const float*)d_in[6];
  const float* Wv = (const float*)d_in[7];
  const float* bv = (const float*)d_in[8];
  const float* Wo = (const float*)d_in[9];
  const float* bo = (const float*)d_in[10];
  const float* proj = (const float*)d_in[11];
  float* out = (float*)d_out;
  float* ws = (float*)d_ws;

  _Float16* KP16 = (_Float16*)(ws + OFF_A);   // kproj then qproj (fp16)
  _Float16* VP16 = (_Float16*)(ws + OFF_B);   // vproj (fp16)
  _Float16* WT = (_Float16*)(ws + OFF_X);
  float* K1P = ws + OFF_X;                    // k1part (WT dead at kv time)
  unsigned short* KVT = (unsigned short*)(ws + OFF_KV);
  float* K1 = ws + OFF_K1;
  float* BMX = ws + OFF_BM;
  float* ST = ws + OFF_ST;
  _Float16* X16 = (_Float16*)(ws + OFF_A16);  // GEMM A staging
  float* KVPT = ws + OFF_A16;                 // kv partials (staging dead)

  dim3 gw(32, 32);

  // 1. k_proj (fp16)
  cvt_f16_kernel<<<2048, 256, 0, stream>>>(key, X16);
  wt_f16_kernel<<<gw, 256, 0, stream>>>(Wk, WT);
  gemm_lds<1><<<256, 512, 0, stream>>>(X16, WT, bk, KP16);
  // 2. stab (reference global max wx_k)
  wxmax_mfma_kernel<<<512, 256, 0, stream>>>(KP16, proj, BMX);
  maxreduce_kernel<<<1, 256, 0, stream>>>(BMX, ST, 512);
  // 3. v_proj (fp16)
  cvt_f16_kernel<<<2048, 256, 0, stream>>>(value, X16);
  wt_f16_kernel<<<gw, 256, 0, stream>>>(Wv, WT);
  gemm_lds<1><<<256, 512, 0, stream>>>(X16, WT, bv, VP16);
  // 4. kv / k1 (KVPT aliases X16 staging — dead; K1P aliases WT — dead)
  kv_mfma_kernel<<<1024, 256, 0, stream>>>(KP16, VP16, proj, ST, KVPT, K1P);
  kvreduce_kernel<<<64, 256, 0, stream>>>(KVPT, K1P, KVT, K1);
  // 5. q_proj (KVPT dead after reduce; kproj dead after kv)
  cvt_f16_kernel<<<2048, 256, 0, stream>>>(query, X16);
  wt_f16_kernel<<<gw, 256, 0, stream>>>(Wq, WT);
  gemm_lds<1><<<256, 512, 0, stream>>>(X16, WT, bq, KP16);
  // 6. out_h -> X16 as fp16 (query staging dead after q_proj gemm)
  qkv_wave_kernel<<<2048, 256, 0, stream>>>(KP16, KVT, K1, proj, X16);
  // 7. output projection (f32 out)
  wt_f16_kernel<<<gw, 256, 0, stream>>>(Wo, WT);
  gemm_lds<0><<<256, 512, 0, stream>>>(X16, WT, bo, out);
}